// Round 7
// baseline (233.073 us; speedup 1.0000x reference)
//
#include <hip/hip_runtime.h>
#include <hip/hip_bf16.h>
#include <math.h>

// Problem constants
#define NB    16
#define NSEQ  2048
#define MROWS (NB*NSEQ)        // 32768
#define NPAD  2176             // gemm1 cols: q [0,1056) + k [1056,2112) + pad
// Within q/k: freq F = h*65+f (0..519, pad 528). gg=F>>4, t=F&15:
//   re at col region*1056 + gg*32 + t, im at +16  -> re/im same lane, 16 apart.
// XQKT: [row F' = region*528 + F][m], 1088 rows.
#define QKT_ROWS 1088

typedef __attribute__((ext_vector_type(8))) short bf16x8;
typedef __attribute__((ext_vector_type(4))) float f32x4;

__device__ __forceinline__ void g2l16(const void* g, void* l) {
    __builtin_amdgcn_global_load_lds(
        (const __attribute__((address_space(1))) void*)g,
        (__attribute__((address_space(3))) void*)l, 16, 0, 0);
}

__device__ __forceinline__ ushort f2bfu(float x) {
    __hip_bfloat16 t = __float2bfloat16(x);
    return *reinterpret_cast<ushort*>(&t);
}

// ---------------------------------------------------------------------------
// Fused small preps: [0,4096) x->Xb cast; [4096,4224) Wv bf16 cast;
// [4224,4744) Gcat (irfft basis @ w_out); [4744,4760) Fcs table.
// ---------------------------------------------------------------------------
__global__ __launch_bounds__(256) void k_misc(const float* __restrict__ x,
                                              const float* __restrict__ wqkv,
                                              const float* __restrict__ wout,
                                              __hip_bfloat16* __restrict__ Xb,
                                              ushort* __restrict__ Wvb,
                                              ushort* __restrict__ Gcat,
                                              ushort* __restrict__ Fcs) {
    __shared__ float tc[128], ts[128];
    int tid = threadIdx.x;
    int bid = blockIdx.x;
    if (bid < 4096) {
        int i = bid * 256 + tid;
        float4 v = ((const float4*)x)[i];
        __hip_bfloat16 o[4] = {__float2bfloat16(v.x), __float2bfloat16(v.y),
                               __float2bfloat16(v.z), __float2bfloat16(v.w)};
        *(ushort4*)((ushort*)Xb + (size_t)i * 4) = *(const ushort4*)o;
    } else if (bid < 4224) {
        int u = bid - 4096;                // 0..127
        float4 v = *(const float4*)(wqkv + (size_t)u * 3072 + 2048 + tid * 4);
        ushort o[4] = {f2bfu(v.x), f2bfu(v.y), f2bfu(v.z), f2bfu(v.w)};
        *(ushort4*)(Wvb + (size_t)u * 1024 + tid * 4) = *(const ushort4*)o;
    } else if (bid < 4744) {
        int hx = bid - 4224;               // 0..519
        if (tid < 128) {
            float a = (float)tid / 64.0f;
            tc[tid] = cospif(a);
            ts[tid] = sinpif(a);
        }
        __syncthreads();
        if (tid < 128) {
            int h = hx / 65, xx = hx - h * 65;
            float w = (xx == 0 || xx == 64) ? (1.0f / 128.0f) : (2.0f / 128.0f);
            float ar = 0.f, ai = 0.f;
            #pragma unroll 8
            for (int d = 0; d < 128; ++d) {
                float wv = wout[(size_t)(h * 128 + d) * 128 + tid];
                int m = (xx * d) & 127;
                ar = fmaf(wv, tc[m], ar);
                ai = fmaf(wv, ts[m], ai);
            }
            ushort* gp = Gcat + ((size_t)(h * 128 + tid)) * 160;
            gp[xx] = f2bfu(ar * w);
            gp[80 + xx] = f2bfu(-ai * w);
            if (xx == 0) {
                for (int k = 65; k < 80; ++k) gp[k] = 0;
                for (int k = 145; k < 160; ++k) gp[k] = 0;
            }
        }
    } else {
        // Fcs[r][y]: r<128 cos(2pi r y/128); r>=128 -sin(...); y>=65 -> 0
        int r = (bid - 4744) * 16 + (tid >> 4);
        int d = r & 127;
        int y0 = (tid & 15) * 6;
        #pragma unroll
        for (int k = 0; k < 6; ++k) {
            int y = y0 + k;
            float v = 0.f;
            if (y < 65) {
                float a = (float)((d * y) & 127) / 64.0f;
                v = (r < 128) ? cospif(a) : -sinpif(a);
            }
            Fcs[r * 96 + y] = f2bfu(v);
        }
    }
}

// ---------------------------------------------------------------------------
// q/k DFT fold into Wt. Grid (32, 2): (reg,h,c-half) x r-half.
// n = reg*1056 + ((F>>4)<<5) + (F&15) + ri*16, F=h*65+f.
// ---------------------------------------------------------------------------
__global__ __launch_bounds__(256) void k_prep_wqk(const float* __restrict__ wqkv,
                                                  __hip_bfloat16* __restrict__ Wt) {
    __shared__ float lw[64][129];
    __shared__ float tc[128], ts[128];
    int tid = threadIdx.x;
    int bid = blockIdx.x;
    int ry = blockIdx.y;
    int reg = bid >> 4;
    int h = (bid >> 1) & 7;
    int c0 = (bid & 1) * 64;
    if (tid < 128) {
        float a = (float)tid / 64.0f;
        tc[tid] = cospif(a);
        ts[tid] = sinpif(a);
    }
    #pragma unroll
    for (int it = 0; it < 8; ++it) {
        int idx = it * 256 + tid;
        int cl = idx >> 5;
        int d4 = (idx & 31) << 2;
        float4 v = *(const float4*)(wqkv + (size_t)(c0 + cl) * 3072 + reg * 1024 + h * 128 + d4);
        lw[cl][d4] = v.x; lw[cl][d4 + 1] = v.y; lw[cl][d4 + 2] = v.z; lw[cl][d4 + 3] = v.w;
    }
    __syncthreads();
    int cl = tid & 63;
    int rr = tid >> 6;
    int rend = ry ? 130 : 65;
    for (int r = ry * 65 + rr; r < rend; r += 4) {
        int f = r >> 1, ri = r & 1;
        float acc = 0.f;
        if (ri) {
            #pragma unroll 16
            for (int d = 0; d < 128; ++d) acc = fmaf(lw[cl][d], -ts[(f * d) & 127], acc);
        } else {
            #pragma unroll 16
            for (int d = 0; d < 128; ++d) acc = fmaf(lw[cl][d], tc[(f * d) & 127], acc);
        }
        int F = h * 65 + f;
        int n = reg * 1056 + ((F >> 4) << 5) + (F & 15) + ri * 16;
        Wt[(size_t)n * 128 + c0 + cl] = __float2bfloat16(acc * (1.0f / 65.0f));
    }
}

// ---------------------------------------------------------------------------
// GEMM1 (MFMA): Xb[32768,128] @ Wt^T (q/k only). 128x128 tile, K=128 one shot.
// Epilogue: (re,im) same lane, adjacent j-tiles -> magnitude -> XQKT packed.
// ---------------------------------------------------------------------------
__global__ __launch_bounds__(256) void k_gemm1m(const __hip_bfloat16* __restrict__ Xb,
                                                const __hip_bfloat16* __restrict__ Wt,
                                                ushort* __restrict__ XQKT) {
    __shared__ ushort As[128 * 128];
    __shared__ ushort Bs[128 * 128];
    int tid = threadIdx.x;
    int wave = tid >> 6, lane = tid & 63;
    int n0 = blockIdx.x * 128;
    int m0 = blockIdx.y * 128;
    const ushort* ga = (const ushort*)Xb + (size_t)m0 * 128;
    const ushort* gb = (const ushort*)Wt + (size_t)n0 * 128;
    #pragma unroll
    for (int it = 0; it < 8; ++it) {
        int q = wave * 512 + it * 64 + lane;
        int row = q >> 4, cp = q & 15;
        int gc = cp ^ (row & 15);
        int lbase = (wave * 512 + it * 64) * 8;
        g2l16(ga + (size_t)row * 128 + gc * 8, As + lbase);
        g2l16(gb + (size_t)row * 128 + gc * 8, Bs + lbase);
    }
    __syncthreads();

    f32x4 acc[4][4];
    #pragma unroll
    for (int i = 0; i < 4; ++i)
        #pragma unroll
        for (int j = 0; j < 4; ++j) acc[i][j] = (f32x4){0.f, 0.f, 0.f, 0.f};

    int lr = lane & 15, lk = lane >> 4;
    int wr = (wave >> 1) * 64, wc = (wave & 1) * 64;
    #pragma unroll
    for (int kk = 0; kk < 4; ++kk) {
        bf16x8 af[4], bfr[4];
        int c = kk * 4 + lk;
        #pragma unroll
        for (int i = 0; i < 4; ++i) {
            int m = wr + i * 16 + lr;
            af[i] = *(const bf16x8*)(As + m * 128 + (c ^ (m & 15)) * 8);
            int n = wc + i * 16 + lr;
            bfr[i] = *(const bf16x8*)(Bs + n * 128 + (c ^ (n & 15)) * 8);
        }
        #pragma unroll
        for (int i = 0; i < 4; ++i)
            #pragma unroll
            for (int j = 0; j < 4; ++j)
                acc[i][j] = __builtin_amdgcn_mfma_f32_16x16x32_bf16(af[i], bfr[j], acc[i][j], 0, 0, 0);
    }

    #pragma unroll
    for (int i = 0; i < 4; ++i) {
        int gr = m0 + wr + i * 16 + lk * 4;
        #pragma unroll
        for (int jp = 0; jp < 2; ++jp) {
            int cb = n0 + wc + jp * 32;
            if (cb < 2112) {
                int region = (cb >= 1056) ? 1 : 0;
                int local = cb - region * 1056;
                int row = region * 528 + ((local >> 5) << 4) + lr;
                f32x4 re = acc[i][2 * jp], im = acc[i][2 * jp + 1];
                union { ushort4 u4; ushort u[4]; } pk;
                #pragma unroll
                for (int r = 0; r < 4; ++r)
                    pk.u[r] = f2bfu(sqrtf(re[r] * re[r] + im[r] * im[r]));
                *(ushort4*)(XQKT + (size_t)row * MROWS + gr) = pk.u4;
            }
        }
    }
}

// ---------------------------------------------------------------------------
// Fused QK^T + softmax per (b,h) block. 2 waves, each covers 1024 e in 16
// substeps of 64 e. Staging: per instr 8 consecutive lanes read one row's
// contiguous 128 B (8 rows/instr -> coalesced), XOR chunk swizzle on the
// GLOBAL side so LDS fragment reads are 2-way conflict-free (pitch 8 chunks).
// LDS per wave: Q rows [0,72), K rows [72,144), pad to 152 (K-tile overreads
// land in-bounds; garbage only pollutes discarded x,y>=72 outputs).
// Cross-wave reduce in LDS (aliases staging), softmax in-block, write bf16
// AttB[80x104] with pads zeroed (direct B-operand for k_TP).
// ---------------------------------------------------------------------------
__global__ __launch_bounds__(128) void k_attsm(const ushort* __restrict__ XQKT,
                                               ushort* __restrict__ AttB) {
    __shared__ ushort S[2 * 9728];         // 2 x 152 rows x 64 ushorts = 38912 B
    int tid = threadIdx.x;
    int wave = tid >> 6, lane = tid & 63;
    int bh = blockIdx.x;
    int b = bh >> 3, h = bh & 7;
    int qrow0 = h * 65, krow0 = 528 + h * 65;
    int lr = lane & 15, quad = lane >> 4;
    ushort* Sw = S + wave * 9728;

    f32x4 acc[5][5];
    #pragma unroll
    for (int i = 0; i < 5; ++i)
        #pragma unroll
        for (int j = 0; j < 5; ++j) acc[i][j] = (f32x4){0.f, 0.f, 0.f, 0.f};

    int lrow = lane >> 3;                  // 0..7 row within instr group
    int gc = (lane & 7) ^ (lrow & 7);      // global chunk (XOR-swizzled)
    size_t ebase0 = (size_t)b * NSEQ + wave * 1024;

    for (int sub = 0; sub < 16; ++sub) {
        __syncthreads();
        size_t ebase = ebase0 + sub * 64;
        #pragma unroll
        for (int i = 0; i < 18; ++i) {
            int qk = (i < 9) ? 0 : 1;
            int r0 = (qk ? (i - 9) : i) * 8;
            int grow = (qk ? krow0 : qrow0) + r0 + lrow;   // max 1054 < 1088
            int ldsrow0 = qk * 72 + r0;
            g2l16(XQKT + (size_t)grow * MROWS + ebase + gc * 8,
                  Sw + ldsrow0 * 64);
        }
        __syncthreads();
        #pragma unroll
        for (int ks = 0; ks < 2; ++ks) {
            int c = ks * 4 + quad;
            bf16x8 af[5], bfr[5];
            #pragma unroll
            for (int t5 = 0; t5 < 5; ++t5) {
                int f = t5 * 16 + lr;
                af[t5]  = *(const bf16x8*)(Sw + f * 64 + ((c ^ (f & 7)) * 8));
                bfr[t5] = *(const bf16x8*)(Sw + (72 + f) * 64 + ((c ^ (f & 7)) * 8));
            }
            #pragma unroll
            for (int tr = 0; tr < 5; ++tr)
                #pragma unroll
                for (int tc = 0; tc < 5; ++tc)
                    acc[tr][tc] = __builtin_amdgcn_mfma_f32_16x16x32_bf16(af[tr], bfr[tc], acc[tr][tc], 0, 0, 0);
        }
    }

    // cross-wave reduce: buf[80][80] f32 aliases S (after barrier)
    __syncthreads();
    float* buf = (float*)S;                // 25600 B <= 38912 B
    if (wave == 0) {
        #pragma unroll
        for (int tr = 0; tr < 5; ++tr)
            #pragma unroll
            for (int tc = 0; tc < 5; ++tc)
                #pragma unroll
                for (int r = 0; r < 4; ++r)
                    buf[(tr * 16 + quad * 4 + r) * 80 + tc * 16 + lr] = acc[tr][tc][r];
    }
    __syncthreads();
    if (wave == 1) {
        #pragma unroll
        for (int tr = 0; tr < 5; ++tr)
            #pragma unroll
            for (int tc = 0; tc < 5; ++tc)
                #pragma unroll
                for (int r = 0; r < 4; ++r)
                    buf[(tr * 16 + quad * 4 + r) * 80 + tc * 16 + lr] += acc[tr][tc][r];
    }
    __syncthreads();

    // softmax rows x (wave-strided) -> AttB bf16 [80 x 104], pads zeroed
    ushort* Ab = AttB + (size_t)bh * 8320;
    for (int xx = wave; xx < 65; xx += 2) {
        float v0 = buf[xx * 80 + lane];
        float v1 = buf[xx * 80 + 64];
        float m = fmaxf(v0, v1);
        #pragma unroll
        for (int off = 32; off >= 1; off >>= 1) m = fmaxf(m, __shfl_xor(m, off));
        float e0 = expf(v0 - m);
        float e1 = expf(v1 - m);
        float s = e0;
        #pragma unroll
        for (int off = 32; off >= 1; off >>= 1) s += __shfl_xor(s, off);
        s += e1;
        float inv = 1.0f / s;
        Ab[xx * 104 + lane] = f2bfu(e0 * inv);
        if (lane == 0) Ab[xx * 104 + 64] = f2bfu(e1 * inv);
        if (lane < 39) Ab[xx * 104 + 65 + lane] = 0;
    }
    for (int i = tid; i < 15 * 104; i += 128) {
        int r = i / 104, c = i - r * 104;
        Ab[(65 + r) * 104 + c] = 0;
    }
}

// ---------------------------------------------------------------------------
// Fused T+P per (chalf, bh) block (reads bf16 AttB straight from global):
// Stage 1: [Fc;Fs][256,96] @ AttB^T -> A3 via LDS (C->A layout, pads zeroed)
// Stage 2: A3[128,160] @ Gcat^T -> Pt[b][c][h*128+d]
// Pitch 168 -> conflict-free fragment reads.
// ---------------------------------------------------------------------------
__global__ __launch_bounds__(256) void k_TP(const ushort* __restrict__ AttB,
                                            const ushort* __restrict__ Fcs,
                                            const ushort* __restrict__ Gcat,
                                            ushort* __restrict__ Pt) {
    __shared__ ushort A3[128 * 168];
    int tid = threadIdx.x;
    int wave = tid >> 6, lane = tid & 63;
    int lr = lane & 15, quad = lane >> 4;
    int chalf = blockIdx.x, bh = blockIdx.y;
    int b = bh >> 3, h = bh & 7;

    uint2 z2; z2.x = 0; z2.y = 0;
    uint2* A3v = (uint2*)A3;
    #pragma unroll 4
    for (int i = tid; i < 128 * 168 / 4; i += 256) A3v[i] = z2;
    __syncthreads();
    const ushort* Ab = AttB + (size_t)bh * 8320;

    // stage 1
    f32x4 acc1[4][5];
    #pragma unroll
    for (int i = 0; i < 4; ++i)
        #pragma unroll
        for (int j = 0; j < 5; ++j) acc1[i][j] = (f32x4){0.f, 0.f, 0.f, 0.f};
    #pragma unroll
    for (int ks = 0; ks < 3; ++ks) {
        bf16x8 af[4], bfr[5];
        #pragma unroll
        for (int mi = 0; mi < 4; ++mi)
            af[mi] = *(const bf16x8*)(Fcs + (size_t)((wave * 4 + mi) * 16 + lr) * 96 + ks * 32 + quad * 8);
        #pragma unroll
        for (int nt = 0; nt < 5; ++nt)
            bfr[nt] = *(const bf16x8*)(Ab + (nt * 16 + lr) * 104 + ks * 32 + quad * 8);
        #pragma unroll
        for (int mi = 0; mi < 4; ++mi)
            #pragma unroll
            for (int nt = 0; nt < 5; ++nt)
                acc1[mi][nt] = __builtin_amdgcn_mfma_f32_16x16x32_bf16(af[mi], bfr[nt], acc1[mi][nt], 0, 0, 0);
    }
    #pragma unroll
    for (int nt = 0; nt < 5; ++nt) {
        int x = nt * 16 + lr;
        if (x < 65) {
            #pragma unroll
            for (int mi = 0; mi < 4; ++mi) {
                int wbase = (wave * 4 + mi) * 16 + quad * 4;
                #pragma unroll
                for (int r = 0; r < 4; ++r) {
                    int which = wbase + r;
                    int d = which & 127;
                    int kc = (which >> 7) * 80 + x;
                    A3[d * 168 + kc] = f2bfu(acc1[mi][nt][r]);
                }
            }
        }
    }
    __syncthreads();

    // stage 2
    f32x4 acc2[2][4];
    #pragma unroll
    for (int i = 0; i < 2; ++i)
        #pragma unroll
        for (int j = 0; j < 4; ++j) acc2[i][j] = (f32x4){0.f, 0.f, 0.f, 0.f};
    const ushort* Gh = Gcat + (size_t)h * 128 * 160;
    #pragma unroll
    for (int ks = 0; ks < 5; ++ks) {
        bf16x8 a2[2], b2[4];
        #pragma unroll
        for (int mi = 0; mi < 2; ++mi)
            a2[mi] = *(const bf16x8*)(A3 + ((wave * 2 + mi) * 16 + lr) * 168 + ks * 32 + quad * 8);
        #pragma unroll
        for (int nt = 0; nt < 4; ++nt)
            b2[nt] = *(const bf16x8*)(Gh + (size_t)(chalf * 64 + nt * 16 + lr) * 160 + ks * 32 + quad * 8);
        #pragma unroll
        for (int mi = 0; mi < 2; ++mi)
            #pragma unroll
            for (int nt = 0; nt < 4; ++nt)
                acc2[mi][nt] = __builtin_amdgcn_mfma_f32_16x16x32_bf16(a2[mi], b2[nt], acc2[mi][nt], 0, 0, 0);
    }
    #pragma unroll
    for (int mi = 0; mi < 2; ++mi) {
        int dbase = (wave * 2 + mi) * 16 + quad * 4;
        #pragma unroll
        for (int nt = 0; nt < 4; ++nt) {
            int c = chalf * 64 + nt * 16 + lr;
            union { ushort4 u4; ushort u[4]; } pk;
            #pragma unroll
            for (int r = 0; r < 4; ++r) pk.u[r] = f2bfu(acc2[mi][nt][r]);
            *(ushort4*)(Pt + ((size_t)(b * 128 + c)) * 1024 + h * 128 + dbase) = pk.u4;
        }
    }
}

// ---------------------------------------------------------------------------
// R_b = Wv @ P_b folded: Rt_b[n][u] = sum_vc Wvb[u][vc] * Pt_b[n][vc].
// One block per batch; M=N=128, K=1024 in 8 steps.
// ---------------------------------------------------------------------------
__global__ __launch_bounds__(256) void k_R(const ushort* __restrict__ Wvb,
                                           const ushort* __restrict__ Pt,
                                           ushort* __restrict__ Rt) {
    __shared__ ushort As[128 * 128];
    __shared__ ushort Bs[128 * 128];
    int tid = threadIdx.x;
    int wave = tid >> 6, lane = tid & 63;
    int b = blockIdx.x;
    const ushort* pb = Pt + (size_t)b * 128 * 1024;

    f32x4 acc[4][4];
    #pragma unroll
    for (int i = 0; i < 4; ++i)
        #pragma unroll
        for (int j = 0; j < 4; ++j) acc[i][j] = (f32x4){0.f, 0.f, 0.f, 0.f};

    int lr = lane & 15, lk = lane >> 4;
    int wr = (wave >> 1) * 64, wc = (wave & 1) * 64;

    for (int k0 = 0; k0 < 1024; k0 += 128) {
        __syncthreads();
        #pragma unroll
        for (int it = 0; it < 8; ++it) {
            int q = wave * 512 + it * 64 + lane;
            int row = q >> 4, cp = q & 15;
            int gc = cp ^ (row & 15);
            int lbase = (wave * 512 + it * 64) * 8;
            g2l16(Wvb + (size_t)row * 1024 + k0 + gc * 8, As + lbase);
            g2l16(pb + (size_t)row * 1024 + k0 + gc * 8, Bs + lbase);
        }
        __syncthreads();
        #pragma unroll
        for (int kk = 0; kk < 4; ++kk) {
            bf16x8 af[4], bfr[4];
            int c = kk * 4 + lk;
            #pragma unroll
            for (int i = 0; i < 4; ++i) {
                int m = wr + i * 16 + lr;
                af[i] = *(const bf16x8*)(As + m * 128 + (c ^ (m & 15)) * 8);
                int n = wc + i * 16 + lr;
                bfr[i] = *(const bf16x8*)(Bs + n * 128 + (c ^ (n & 15)) * 8);
            }
            #pragma unroll
            for (int i = 0; i < 4; ++i)
                #pragma unroll
                for (int j = 0; j < 4; ++j)
                    acc[i][j] = __builtin_amdgcn_mfma_f32_16x16x32_bf16(af[i], bfr[j], acc[i][j], 0, 0, 0);
        }
    }
    #pragma unroll
    for (int i = 0; i < 4; ++i) {
        int ubase = wr + i * 16 + lk * 4;
        #pragma unroll
        for (int j = 0; j < 4; ++j) {
            int n = wc + j * 16 + lr;
            union { ushort4 u4; ushort u[4]; } pk;
            #pragma unroll
            for (int r = 0; r < 4; ++r) pk.u[r] = f2bfu(acc[i][j][r]);
            *(ushort4*)(Rt + (size_t)b * 16384 + n * 128 + ubase) = pk.u4;
        }
    }
}

// ---------------------------------------------------------------------------
// out = Xb @ Rt_b^T + bias. M=32768 (128/block), N=128, K=128 one shot.
// ---------------------------------------------------------------------------
__global__ __launch_bounds__(256) void k_out(const __hip_bfloat16* __restrict__ Xb,
                                             const ushort* __restrict__ Rt,
                                             const float* __restrict__ bout,
                                             float* __restrict__ out) {
    __shared__ ushort As[128 * 128];
    __shared__ ushort Bs[128 * 128];
    int tid = threadIdx.x;
    int wave = tid >> 6, lane = tid & 63;
    int m0 = blockIdx.x * 128;
    int b = blockIdx.x >> 4;
    const ushort* ga = (const ushort*)Xb + (size_t)m0 * 128;
    const ushort* gb = Rt + (size_t)b * 16384;
    #pragma unroll
    for (int it = 0; it < 8; ++it) {
        int q = wave * 512 + it * 64 + lane;
        int row = q >> 4, cp = q & 15;
        int gc = cp ^ (row & 15);
        int lbase = (wave * 512 + it * 64) * 8;
        g2l16(ga + (size_t)row * 128 + gc * 8, As + lbase);
        g2l16(gb + (size_t)row * 128 + gc * 8, Bs + lbase);
    }
    __syncthreads();

    f32x4 acc[4][4];
    #pragma unroll
    for (int i = 0; i < 4; ++i)
        #pragma unroll
        for (int j = 0; j < 4; ++j) acc[i][j] = (f32x4){0.f, 0.f, 0.f, 0.f};

    int lr = lane & 15, lk = lane >> 4;
    int wr = (wave >> 1) * 64, wc = (wave & 1) * 64;
    #pragma unroll
    for (int kk = 0; kk < 4; ++kk) {
        bf16x8 af[4], bfr[4];
        int c = kk * 4 + lk;
        #pragma unroll
        for (int i = 0; i < 4; ++i) {
            int m = wr + i * 16 + lr;
            af[i] = *(const bf16x8*)(As + m * 128 + (c ^ (m & 15)) * 8);
            int n = wc + i * 16 + lr;
            bfr[i] = *(const bf16x8*)(Bs + n * 128 + (c ^ (n & 15)) * 8);
        }
        #pragma unroll
        for (int i = 0; i < 4; ++i)
            #pragma unroll
            for (int j = 0; j < 4; ++j)
                acc[i][j] = __builtin_amdgcn_mfma_f32_16x16x32_bf16(af[i], bfr[j], acc[i][j], 0, 0, 0);
    }

    #pragma unroll
    for (int i = 0; i < 4; ++i) {
        int gr = m0 + wr + i * 16 + lk * 4;
        #pragma unroll
        for (int j = 0; j < 4; ++j) {
            int gcol = wc + j * 16 + lr;
            float bias = bout[gcol];
            #pragma unroll
            for (int r = 0; r < 4; ++r)
                out[(size_t)(gr + r) * 128 + gcol] = acc[i][j][r] + bias;
        }
    }
}

extern "C" void kernel_launch(void* const* d_in, const int* in_sizes, int n_in,
                              void* d_out, int out_size, void* d_ws, size_t ws_size,
                              hipStream_t stream) {
    const float* x    = (const float*)d_in[0];
    const float* wqkv = (const float*)d_in[1];
    const float* wout = (const float*)d_in[2];
    const float* bout = (const float*)d_in[3];
    float* out = (float*)d_out;

    char* ws = (char*)d_ws;
    size_t off = 0;
    auto alloc = [&](size_t bytes) -> void* {
        void* p = (void*)(ws + off);
        off += (bytes + 255) & ~(size_t)255;
        return p;
    };
    __hip_bfloat16* Wt = (__hip_bfloat16*)alloc((size_t)NPAD * 128 * 2);       // 0.56 MB
    ushort* Gcat = (ushort*)alloc((size_t)8 * 128 * 160 * 2);                  // 320 KB
    ushort* Fcs  = (ushort*)alloc((size_t)256 * 96 * 2);                       // 48 KB
    ushort* Wvb  = (ushort*)alloc((size_t)128 * 1024 * 2);                     // 256 KB
    ushort* XQKT = (ushort*)alloc((size_t)QKT_ROWS * MROWS * 2);               // 71.3 MB
    __hip_bfloat16* Xb = (__hip_bfloat16*)alloc((size_t)MROWS * 128 * 2);      // 8.4 MB
    ushort* AttB = (ushort*)alloc((size_t)128 * 8320 * 2);                     // 2.13 MB
    ushort* Pt  = (ushort*)alloc((size_t)16 * 128 * 1024 * 2);                 // 4.2 MB
    ushort* Rt  = (ushort*)alloc((size_t)16 * 128 * 128 * 2);                  // 512 KB

    k_misc<<<dim3(4760), 256, 0, stream>>>(x, wqkv, wout, Xb, Wvb, Gcat, Fcs);
    k_prep_wqk<<<dim3(32, 2), 256, 0, stream>>>(wqkv, Wt);
    k_gemm1m<<<dim3(17, 256), 256, 0, stream>>>(Xb, Wt, XQKT);
    k_attsm<<<dim3(128), 128, 0, stream>>>(XQKT, AttB);
    k_TP<<<dim3(2, 128), 256, 0, stream>>>(AttB, Fcs, Gcat, Pt);
    k_R<<<dim3(16), 256, 0, stream>>>(Wvb, Pt, Rt);
    k_out<<<dim3(256), 256, 0, stream>>>(Xb, Rt, bout, out);
}

// Round 8
// 212.685 us; speedup vs baseline: 1.0959x; 1.0959x over previous
//
#include <hip/hip_runtime.h>
#include <hip/hip_bf16.h>
#include <math.h>

// Problem constants
#define NB    16
#define NSEQ  2048
#define MROWS (NB*NSEQ)        // 32768
#define NPAD  2176             // gemm1 cols: q [0,1056) + k [1056,2112) + pad
// Within q/k: freq F = h*65+f (0..519, pad 528). gg=F>>4, t=F&15:
//   re at col region*1056 + gg*32 + t, im at +16  -> re/im same lane, 16 apart.
// XQKT: [row F' = region*528 + F][m], 1088 rows.
#define QKT_ROWS 1088

typedef __attribute__((ext_vector_type(8))) short bf16x8;
typedef __attribute__((ext_vector_type(4))) float f32x4;

__device__ __forceinline__ void g2l16(const void* g, void* l) {
    __builtin_amdgcn_global_load_lds(
        (const __attribute__((address_space(1))) void*)g,
        (__attribute__((address_space(3))) void*)l, 16, 0, 0);
}

__device__ __forceinline__ ushort f2bfu(float x) {
    __hip_bfloat16 t = __float2bfloat16(x);
    return *reinterpret_cast<ushort*>(&t);
}

// ---------------------------------------------------------------------------
// Fused preps: [0,4096) x->Xb cast; [4096,4224) Wv bf16 cast;
// [4224,4744) Gcat; [4744,4760) Fcs table; [4760,4824) q/k DFT fold into Wt.
// ---------------------------------------------------------------------------
__global__ __launch_bounds__(256) void k_misc(const float* __restrict__ x,
                                              const float* __restrict__ wqkv,
                                              const float* __restrict__ wout,
                                              __hip_bfloat16* __restrict__ Xb,
                                              ushort* __restrict__ Wvb,
                                              ushort* __restrict__ Gcat,
                                              ushort* __restrict__ Fcs,
                                              __hip_bfloat16* __restrict__ Wt) {
    __shared__ float tc[128], ts[128];
    __shared__ float lw[64][129];
    int tid = threadIdx.x;
    int bid = blockIdx.x;
    if (bid < 4096) {
        int i = bid * 256 + tid;
        float4 v = ((const float4*)x)[i];
        __hip_bfloat16 o[4] = {__float2bfloat16(v.x), __float2bfloat16(v.y),
                               __float2bfloat16(v.z), __float2bfloat16(v.w)};
        *(ushort4*)((ushort*)Xb + (size_t)i * 4) = *(const ushort4*)o;
    } else if (bid < 4224) {
        int u = bid - 4096;                // 0..127
        float4 v = *(const float4*)(wqkv + (size_t)u * 3072 + 2048 + tid * 4);
        ushort o[4] = {f2bfu(v.x), f2bfu(v.y), f2bfu(v.z), f2bfu(v.w)};
        *(ushort4*)(Wvb + (size_t)u * 1024 + tid * 4) = *(const ushort4*)o;
    } else if (bid < 4744) {
        int hx = bid - 4224;               // 0..519
        if (tid < 128) {
            float a = (float)tid / 64.0f;
            tc[tid] = cospif(a);
            ts[tid] = sinpif(a);
        }
        __syncthreads();
        if (tid < 128) {
            int h = hx / 65, xx = hx - h * 65;
            float w = (xx == 0 || xx == 64) ? (1.0f / 128.0f) : (2.0f / 128.0f);
            float ar = 0.f, ai = 0.f;
            #pragma unroll 8
            for (int d = 0; d < 128; ++d) {
                float wv = wout[(size_t)(h * 128 + d) * 128 + tid];
                int m = (xx * d) & 127;
                ar = fmaf(wv, tc[m], ar);
                ai = fmaf(wv, ts[m], ai);
            }
            ushort* gp = Gcat + ((size_t)(h * 128 + tid)) * 160;
            gp[xx] = f2bfu(ar * w);
            gp[80 + xx] = f2bfu(-ai * w);
            if (xx == 0) {
                for (int k = 65; k < 80; ++k) gp[k] = 0;
                for (int k = 145; k < 160; ++k) gp[k] = 0;
            }
        }
    } else if (bid < 4760) {
        // Fcs[r][y]: r<128 cos(2pi r y/128); r>=128 -sin(...); y>=65 -> 0
        int r = (bid - 4744) * 16 + (tid >> 4);
        int d = r & 127;
        int y0 = (tid & 15) * 6;
        #pragma unroll
        for (int k = 0; k < 6; ++k) {
            int y = y0 + k;
            float v = 0.f;
            if (y < 65) {
                float a = (float)((d * y) & 127) / 64.0f;
                v = (r < 128) ? cospif(a) : -sinpif(a);
            }
            Fcs[r * 96 + y] = f2bfu(v);
        }
    } else {
        // q/k DFT fold: idx = (reg,h,c-half) x r-half
        int idx = bid - 4760;              // 0..63
        int sub = idx & 31;
        int ry = idx >> 5;
        int reg = sub >> 4;
        int h = (sub >> 1) & 7;
        int c0 = (sub & 1) * 64;
        if (tid < 128) {
            float a = (float)tid / 64.0f;
            tc[tid] = cospif(a);
            ts[tid] = sinpif(a);
        }
        #pragma unroll
        for (int it = 0; it < 8; ++it) {
            int i2 = it * 256 + tid;
            int cl = i2 >> 5;
            int d4 = (i2 & 31) << 2;
            float4 v = *(const float4*)(wqkv + (size_t)(c0 + cl) * 3072 + reg * 1024 + h * 128 + d4);
            lw[cl][d4] = v.x; lw[cl][d4 + 1] = v.y; lw[cl][d4 + 2] = v.z; lw[cl][d4 + 3] = v.w;
        }
        __syncthreads();
        int cl = tid & 63;
        int rr = tid >> 6;
        int rend = ry ? 130 : 65;
        for (int r = ry * 65 + rr; r < rend; r += 4) {
            int f = r >> 1, ri = r & 1;
            float acc = 0.f;
            if (ri) {
                #pragma unroll 16
                for (int d = 0; d < 128; ++d) acc = fmaf(lw[cl][d], -ts[(f * d) & 127], acc);
            } else {
                #pragma unroll 16
                for (int d = 0; d < 128; ++d) acc = fmaf(lw[cl][d], tc[(f * d) & 127], acc);
            }
            int F = h * 65 + f;
            int n = reg * 1056 + ((F >> 4) << 5) + (F & 15) + ri * 16;
            Wt[(size_t)n * 128 + c0 + cl] = __float2bfloat16(acc * (1.0f / 65.0f));
        }
    }
}

// ---------------------------------------------------------------------------
// GEMM1 (MFMA): Xb[32768,128] @ Wt^T (q/k only). 128x128 tile, K=128 one shot.
// Epilogue: (re,im) same lane, adjacent j-tiles -> magnitude -> XQKT packed.
// ---------------------------------------------------------------------------
__global__ __launch_bounds__(256) void k_gemm1m(const __hip_bfloat16* __restrict__ Xb,
                                                const __hip_bfloat16* __restrict__ Wt,
                                                ushort* __restrict__ XQKT) {
    __shared__ ushort As[128 * 128];
    __shared__ ushort Bs[128 * 128];
    int tid = threadIdx.x;
    int wave = tid >> 6, lane = tid & 63;
    int n0 = blockIdx.x * 128;
    int m0 = blockIdx.y * 128;
    const ushort* ga = (const ushort*)Xb + (size_t)m0 * 128;
    const ushort* gb = (const ushort*)Wt + (size_t)n0 * 128;
    #pragma unroll
    for (int it = 0; it < 8; ++it) {
        int q = wave * 512 + it * 64 + lane;
        int row = q >> 4, cp = q & 15;
        int gc = cp ^ (row & 15);
        int lbase = (wave * 512 + it * 64) * 8;
        g2l16(ga + (size_t)row * 128 + gc * 8, As + lbase);
        g2l16(gb + (size_t)row * 128 + gc * 8, Bs + lbase);
    }
    __syncthreads();

    f32x4 acc[4][4];
    #pragma unroll
    for (int i = 0; i < 4; ++i)
        #pragma unroll
        for (int j = 0; j < 4; ++j) acc[i][j] = (f32x4){0.f, 0.f, 0.f, 0.f};

    int lr = lane & 15, lk = lane >> 4;
    int wr = (wave >> 1) * 64, wc = (wave & 1) * 64;
    #pragma unroll
    for (int kk = 0; kk < 4; ++kk) {
        bf16x8 af[4], bfr[4];
        int c = kk * 4 + lk;
        #pragma unroll
        for (int i = 0; i < 4; ++i) {
            int m = wr + i * 16 + lr;
            af[i] = *(const bf16x8*)(As + m * 128 + (c ^ (m & 15)) * 8);
            int n = wc + i * 16 + lr;
            bfr[i] = *(const bf16x8*)(Bs + n * 128 + (c ^ (n & 15)) * 8);
        }
        #pragma unroll
        for (int i = 0; i < 4; ++i)
            #pragma unroll
            for (int j = 0; j < 4; ++j)
                acc[i][j] = __builtin_amdgcn_mfma_f32_16x16x32_bf16(af[i], bfr[j], acc[i][j], 0, 0, 0);
    }

    #pragma unroll
    for (int i = 0; i < 4; ++i) {
        int gr = m0 + wr + i * 16 + lk * 4;
        #pragma unroll
        for (int jp = 0; jp < 2; ++jp) {
            int cb = n0 + wc + jp * 32;
            if (cb < 2112) {
                int region = (cb >= 1056) ? 1 : 0;
                int local = cb - region * 1056;
                int row = region * 528 + ((local >> 5) << 4) + lr;
                f32x4 re = acc[i][2 * jp], im = acc[i][2 * jp + 1];
                union { ushort4 u4; ushort u[4]; } pk;
                #pragma unroll
                for (int r = 0; r < 4; ++r)
                    pk.u[r] = f2bfu(sqrtf(re[r] * re[r] + im[r] * im[r]));
                *(ushort4*)(XQKT + (size_t)row * MROWS + gr) = pk.u4;
            }
        }
    }
}

// ---------------------------------------------------------------------------
// QK^T partials via MFMA. Grid (bh=128, ch=8 e-chunks of 256), 5 waves/block.
// Stage once per block: Q rows [0,65], K rows [72,137], pitch 32 chunks of
// 16B (512 B/row). Each staging instr: 2 rows x 32 lanes contiguous 512 B ->
// coalesced (8 lines/instr). XOR chunk swizzle on global side; fragment
// ds_read_b128: 8 consecutive lanes hit 8 distinct bank groups -> clean.
// Wave w computes output tile-row w (5 tiles of 16x16 over full 256 e).
// Unstaged pad rows (66-71, 138-143) only feed discarded x,y>=66 outputs.
// attp partial layout per (bh,ch): [80][80] f32.
// ---------------------------------------------------------------------------
__global__ __launch_bounds__(320) void k_attq(const ushort* __restrict__ XQKT,
                                              float* __restrict__ attp) {
    __shared__ ushort S[144 * 256];        // 73728 B
    int tid = threadIdx.x;
    int wave = tid >> 6, lane = tid & 63;
    int bh = blockIdx.x, ch = blockIdx.y;
    int b = bh >> 3, h = bh & 7;
    int qrow0 = h * 65, krow0 = 528 + h * 65;
    int lr = lane & 15, quad = lane >> 4;
    size_t ebase = (size_t)b * NSEQ + ch * 256;
    int lrow = lane >> 5;                  // 0/1: row within staging pair
    int lch = lane & 31;                   // chunk within row

    for (int i = wave; i < 66; i += 5) {
        int qk = (i >= 33) ? 1 : 0;
        int pi = i - 33 * qk;
        int lrow0 = qk * 72 + pi * 2;
        int row = lrow0 + lrow;
        int grow = (qk ? krow0 : qrow0) + pi * 2 + lrow;   // max 1048 < 1088
        int gc = lch ^ (row & 7);
        g2l16(XQKT + (size_t)grow * MROWS + ebase + gc * 8, S + lrow0 * 256);
    }
    __syncthreads();

    f32x4 acc[5];
    #pragma unroll
    for (int j = 0; j < 5; ++j) acc[j] = (f32x4){0.f, 0.f, 0.f, 0.f};
    int tr = wave;
    int arow = tr * 16 + lr;
    #pragma unroll
    for (int ks = 0; ks < 8; ++ks) {
        int pc = (ks * 4 + quad) ^ (lr & 7);
        bf16x8 af = *(const bf16x8*)(S + arow * 256 + pc * 8);
        bf16x8 bfr[5];
        #pragma unroll
        for (int tc = 0; tc < 5; ++tc)
            bfr[tc] = *(const bf16x8*)(S + (72 + tc * 16 + lr) * 256 + pc * 8);
        #pragma unroll
        for (int tc = 0; tc < 5; ++tc)
            acc[tc] = __builtin_amdgcn_mfma_f32_16x16x32_bf16(af, bfr[tc], acc[tc], 0, 0, 0);
    }

    float* outp = attp + ((size_t)bh * 8 + ch) * 6400;
    #pragma unroll
    for (int tc = 0; tc < 5; ++tc)
        #pragma unroll
        for (int r = 0; r < 4; ++r)
            outp[(tr * 16 + quad * 4 + r) * 80 + tc * 16 + lr] = acc[tc][r];
}

// ---------------------------------------------------------------------------
// Sum 8 partials + softmax over y -> AttB bf16 [80x104] zero-padded.
// Grid (80, 128): xx<65 softmax row; xx>=65 zero pad row.
// ---------------------------------------------------------------------------
__global__ void k_softmax(const float* __restrict__ attp, ushort* __restrict__ AttB) {
    int xx = blockIdx.x;                   // 0..79
    int bh = blockIdx.y;                   // 0..127
    int lane = threadIdx.x;                // 64
    ushort* Ab = AttB + (size_t)bh * 8320;
    if (xx >= 65) {
        Ab[xx * 104 + lane] = 0;
        if (lane < 40) Ab[xx * 104 + 64 + lane] = 0;
        return;
    }
    const float* base = attp + (size_t)bh * 8 * 6400 + xx * 80;
    float v0 = 0.f, v1 = 0.f;
    #pragma unroll
    for (int c = 0; c < 8; ++c) {
        v0 += base[(size_t)c * 6400 + lane];
        if (lane == 0) v1 += base[(size_t)c * 6400 + 64];
    }
    float v1b = __shfl(v1, 0);
    float m = fmaxf(v0, v1b);
    #pragma unroll
    for (int off = 32; off >= 1; off >>= 1) m = fmaxf(m, __shfl_xor(m, off));
    float e0 = expf(v0 - m);
    float e1 = expf(v1b - m);
    float s = e0;
    #pragma unroll
    for (int off = 32; off >= 1; off >>= 1) s += __shfl_xor(s, off);
    s += e1;
    float inv = 1.0f / s;
    Ab[xx * 104 + lane] = f2bfu(e0 * inv);
    if (lane == 0) Ab[xx * 104 + 64] = f2bfu(e1 * inv);
    if (lane < 39) Ab[xx * 104 + 65 + lane] = 0;
}

// ---------------------------------------------------------------------------
// Fused T+P per (chalf, bh) block (reads bf16 AttB straight from global):
// Stage 1: [Fc;Fs][256,96] @ AttB^T -> A3 via LDS (C->A layout, pads zeroed)
// Stage 2: A3[128,160] @ Gcat^T -> Pt[b][c][h*128+d]
// ---------------------------------------------------------------------------
__global__ __launch_bounds__(256) void k_TP(const ushort* __restrict__ AttB,
                                            const ushort* __restrict__ Fcs,
                                            const ushort* __restrict__ Gcat,
                                            ushort* __restrict__ Pt) {
    __shared__ ushort A3[128 * 168];
    int tid = threadIdx.x;
    int wave = tid >> 6, lane = tid & 63;
    int lr = lane & 15, quad = lane >> 4;
    int chalf = blockIdx.x, bh = blockIdx.y;
    int b = bh >> 3, h = bh & 7;

    uint2 z2; z2.x = 0; z2.y = 0;
    uint2* A3v = (uint2*)A3;
    #pragma unroll 4
    for (int i = tid; i < 128 * 168 / 4; i += 256) A3v[i] = z2;
    __syncthreads();
    const ushort* Ab = AttB + (size_t)bh * 8320;

    // stage 1
    f32x4 acc1[4][5];
    #pragma unroll
    for (int i = 0; i < 4; ++i)
        #pragma unroll
        for (int j = 0; j < 5; ++j) acc1[i][j] = (f32x4){0.f, 0.f, 0.f, 0.f};
    #pragma unroll
    for (int ks = 0; ks < 3; ++ks) {
        bf16x8 af[4], bfr[5];
        #pragma unroll
        for (int mi = 0; mi < 4; ++mi)
            af[mi] = *(const bf16x8*)(Fcs + (size_t)((wave * 4 + mi) * 16 + lr) * 96 + ks * 32 + quad * 8);
        #pragma unroll
        for (int nt = 0; nt < 5; ++nt)
            bfr[nt] = *(const bf16x8*)(Ab + (nt * 16 + lr) * 104 + ks * 32 + quad * 8);
        #pragma unroll
        for (int mi = 0; mi < 4; ++mi)
            #pragma unroll
            for (int nt = 0; nt < 5; ++nt)
                acc1[mi][nt] = __builtin_amdgcn_mfma_f32_16x16x32_bf16(af[mi], bfr[nt], acc1[mi][nt], 0, 0, 0);
    }
    #pragma unroll
    for (int nt = 0; nt < 5; ++nt) {
        int x = nt * 16 + lr;
        if (x < 65) {
            #pragma unroll
            for (int mi = 0; mi < 4; ++mi) {
                int wbase = (wave * 4 + mi) * 16 + quad * 4;
                #pragma unroll
                for (int r = 0; r < 4; ++r) {
                    int which = wbase + r;
                    int d = which & 127;
                    int kc = (which >> 7) * 80 + x;
                    A3[d * 168 + kc] = f2bfu(acc1[mi][nt][r]);
                }
            }
        }
    }
    __syncthreads();

    // stage 2
    f32x4 acc2[2][4];
    #pragma unroll
    for (int i = 0; i < 2; ++i)
        #pragma unroll
        for (int j = 0; j < 4; ++j) acc2[i][j] = (f32x4){0.f, 0.f, 0.f, 0.f};
    const ushort* Gh = Gcat + (size_t)h * 128 * 160;
    #pragma unroll
    for (int ks = 0; ks < 5; ++ks) {
        bf16x8 a2[2], b2[4];
        #pragma unroll
        for (int mi = 0; mi < 2; ++mi)
            a2[mi] = *(const bf16x8*)(A3 + ((wave * 2 + mi) * 16 + lr) * 168 + ks * 32 + quad * 8);
        #pragma unroll
        for (int nt = 0; nt < 4; ++nt)
            b2[nt] = *(const bf16x8*)(Gh + (size_t)(chalf * 64 + nt * 16 + lr) * 160 + ks * 32 + quad * 8);
        #pragma unroll
        for (int mi = 0; mi < 2; ++mi)
            #pragma unroll
            for (int nt = 0; nt < 4; ++nt)
                acc2[mi][nt] = __builtin_amdgcn_mfma_f32_16x16x32_bf16(a2[mi], b2[nt], acc2[mi][nt], 0, 0, 0);
    }
    #pragma unroll
    for (int mi = 0; mi < 2; ++mi) {
        int dbase = (wave * 2 + mi) * 16 + quad * 4;
        #pragma unroll
        for (int nt = 0; nt < 4; ++nt) {
            int c = chalf * 64 + nt * 16 + lr;
            union { ushort4 u4; ushort u[4]; } pk;
            #pragma unroll
            for (int r = 0; r < 4; ++r) pk.u[r] = f2bfu(acc2[mi][nt][r]);
            *(ushort4*)(Pt + ((size_t)(b * 128 + c)) * 1024 + h * 128 + dbase) = pk.u4;
        }
    }
}

// ---------------------------------------------------------------------------
// R_b = Wv @ P_b folded: Rt_b[n][u] = sum_vc Wvb[u][vc] * Pt_b[n][vc].
// ---------------------------------------------------------------------------
__global__ __launch_bounds__(256) void k_R(const ushort* __restrict__ Wvb,
                                           const ushort* __restrict__ Pt,
                                           ushort* __restrict__ Rt) {
    __shared__ ushort As[128 * 128];
    __shared__ ushort Bs[128 * 128];
    int tid = threadIdx.x;
    int wave = tid >> 6, lane = tid & 63;
    int b = blockIdx.x;
    const ushort* pb = Pt + (size_t)b * 128 * 1024;

    f32x4 acc[4][4];
    #pragma unroll
    for (int i = 0; i < 4; ++i)
        #pragma unroll
        for (int j = 0; j < 4; ++j) acc[i][j] = (f32x4){0.f, 0.f, 0.f, 0.f};

    int lr = lane & 15, lk = lane >> 4;
    int wr = (wave >> 1) * 64, wc = (wave & 1) * 64;

    for (int k0 = 0; k0 < 1024; k0 += 128) {
        __syncthreads();
        #pragma unroll
        for (int it = 0; it < 8; ++it) {
            int q = wave * 512 + it * 64 + lane;
            int row = q >> 4, cp = q & 15;
            int gc = cp ^ (row & 15);
            int lbase = (wave * 512 + it * 64) * 8;
            g2l16(Wvb + (size_t)row * 1024 + k0 + gc * 8, As + lbase);
            g2l16(pb + (size_t)row * 1024 + k0 + gc * 8, Bs + lbase);
        }
        __syncthreads();
        #pragma unroll
        for (int kk = 0; kk < 4; ++kk) {
            bf16x8 af[4], bfr[4];
            int c = kk * 4 + lk;
            #pragma unroll
            for (int i = 0; i < 4; ++i) {
                int m = wr + i * 16 + lr;
                af[i] = *(const bf16x8*)(As + m * 128 + (c ^ (m & 15)) * 8);
                int n = wc + i * 16 + lr;
                bfr[i] = *(const bf16x8*)(Bs + n * 128 + (c ^ (n & 15)) * 8);
            }
            #pragma unroll
            for (int i = 0; i < 4; ++i)
                #pragma unroll
                for (int j = 0; j < 4; ++j)
                    acc[i][j] = __builtin_amdgcn_mfma_f32_16x16x32_bf16(af[i], bfr[j], acc[i][j], 0, 0, 0);
        }
    }
    #pragma unroll
    for (int i = 0; i < 4; ++i) {
        int ubase = wr + i * 16 + lk * 4;
        #pragma unroll
        for (int j = 0; j < 4; ++j) {
            int n = wc + j * 16 + lr;
            union { ushort4 u4; ushort u[4]; } pk;
            #pragma unroll
            for (int r = 0; r < 4; ++r) pk.u[r] = f2bfu(acc[i][j][r]);
            *(ushort4*)(Rt + (size_t)b * 16384 + n * 128 + ubase) = pk.u4;
        }
    }
}

// ---------------------------------------------------------------------------
// out = Xb @ Rt_b^T + bias. M=32768 (128/block), N=128, K=128 one shot.
// ---------------------------------------------------------------------------
__global__ __launch_bounds__(256) void k_out(const __hip_bfloat16* __restrict__ Xb,
                                             const ushort* __restrict__ Rt,
                                             const float* __restrict__ bout,
                                             float* __restrict__ out) {
    __shared__ ushort As[128 * 128];
    __shared__ ushort Bs[128 * 128];
    int tid = threadIdx.x;
    int wave = tid >> 6, lane = tid & 63;
    int m0 = blockIdx.x * 128;
    int b = blockIdx.x >> 4;
    const ushort* ga = (const ushort*)Xb + (size_t)m0 * 128;
    const ushort* gb = Rt + (size_t)b * 16384;
    #pragma unroll
    for (int it = 0; it < 8; ++it) {
        int q = wave * 512 + it * 64 + lane;
        int row = q >> 4, cp = q & 15;
        int gc = cp ^ (row & 15);
        int lbase = (wave * 512 + it * 64) * 8;
        g2l16(ga + (size_t)row * 128 + gc * 8, As + lbase);
        g2l16(gb + (size_t)row * 128 + gc * 8, Bs + lbase);
    }
    __syncthreads();

    f32x4 acc[4][4];
    #pragma unroll
    for (int i = 0; i < 4; ++i)
        #pragma unroll
        for (int j = 0; j < 4; ++j) acc[i][j] = (f32x4){0.f, 0.f, 0.f, 0.f};

    int lr = lane & 15, lk = lane >> 4;
    int wr = (wave >> 1) * 64, wc = (wave & 1) * 64;
    #pragma unroll
    for (int kk = 0; kk < 4; ++kk) {
        bf16x8 af[4], bfr[4];
        int c = kk * 4 + lk;
        #pragma unroll
        for (int i = 0; i < 4; ++i) {
            int m = wr + i * 16 + lr;
            af[i] = *(const bf16x8*)(As + m * 128 + (c ^ (m & 15)) * 8);
            int n = wc + i * 16 + lr;
            bfr[i] = *(const bf16x8*)(Bs + n * 128 + (c ^ (n & 15)) * 8);
        }
        #pragma unroll
        for (int i = 0; i < 4; ++i)
            #pragma unroll
            for (int j = 0; j < 4; ++j)
                acc[i][j] = __builtin_amdgcn_mfma_f32_16x16x32_bf16(af[i], bfr[j], acc[i][j], 0, 0, 0);
    }

    #pragma unroll
    for (int i = 0; i < 4; ++i) {
        int gr = m0 + wr + i * 16 + lk * 4;
        #pragma unroll
        for (int j = 0; j < 4; ++j) {
            int gcol = wc + j * 16 + lr;
            float bias = bout[gcol];
            #pragma unroll
            for (int r = 0; r < 4; ++r)
                out[(size_t)(gr + r) * 128 + gcol] = acc[i][j][r] + bias;
        }
    }
}

extern "C" void kernel_launch(void* const* d_in, const int* in_sizes, int n_in,
                              void* d_out, int out_size, void* d_ws, size_t ws_size,
                              hipStream_t stream) {
    const float* x    = (const float*)d_in[0];
    const float* wqkv = (const float*)d_in[1];
    const float* wout = (const float*)d_in[2];
    const float* bout = (const float*)d_in[3];
    float* out = (float*)d_out;

    char* ws = (char*)d_ws;
    size_t off = 0;
    auto alloc = [&](size_t bytes) -> void* {
        void* p = (void*)(ws + off);
        off += (bytes + 255) & ~(size_t)255;
        return p;
    };
    __hip_bfloat16* Wt = (__hip_bfloat16*)alloc((size_t)NPAD * 128 * 2);       // 0.56 MB
    ushort* Gcat = (ushort*)alloc((size_t)8 * 128 * 160 * 2);                  // 320 KB
    ushort* Fcs  = (ushort*)alloc((size_t)256 * 96 * 2);                       // 48 KB
    ushort* Wvb  = (ushort*)alloc((size_t)128 * 1024 * 2);                     // 256 KB
    ushort* XQKT = (ushort*)alloc((size_t)QKT_ROWS * MROWS * 2);               // 71.3 MB
    __hip_bfloat16* Xb = (__hip_bfloat16*)alloc((size_t)MROWS * 128 * 2);      // 8.4 MB
    float* attp = (float*)alloc((size_t)128 * 8 * 6400 * 4);                   // 26.2 MB
    ushort* AttB = (ushort*)alloc((size_t)128 * 8320 * 2);                     // 2.13 MB
    ushort* Pt  = (ushort*)alloc((size_t)16 * 128 * 1024 * 2);                 // 4.2 MB
    ushort* Rt  = (ushort*)alloc((size_t)16 * 128 * 128 * 2);                  // 512 KB

    k_misc<<<dim3(4824), 256, 0, stream>>>(x, wqkv, wout, Xb, Wvb, Gcat, Fcs, Wt);
    k_gemm1m<<<dim3(17, 256), 256, 0, stream>>>(Xb, Wt, XQKT);
    k_attq<<<dim3(128, 8), 320, 0, stream>>>(XQKT, attp);
    k_softmax<<<dim3(80, 128), 64, 0, stream>>>(attp, AttB);
    k_TP<<<dim3(2, 128), 256, 0, stream>>>(AttB, Fcs, Gcat, Pt);
    k_R<<<dim3(16), 256, 0, stream>>>(Wvb, Pt, Rt);
    k_out<<<dim3(256), 256, 0, stream>>>(Xb, Rt, bout, out);
}

// Round 9
// 184.177 us; speedup vs baseline: 1.2655x; 1.1548x over previous
//
#include <hip/hip_runtime.h>
#include <hip/hip_bf16.h>
#include <math.h>

// Problem constants
#define NB    16
#define NSEQ  2048
#define MROWS (NB*NSEQ)        // 32768
#define NPAD  2176             // gemm1 cols: q [0,1056) + k [1056,2112) + pad
// Within q/k: freq F = h*65+f (0..519, pad 528). gg=F>>4, t=F&15:
//   re at col region*1056 + gg*32 + t, im at +16  -> re/im same lane, 16 apart.
// XQKT: [row F' = region*528 + F][m], 1088 rows.
#define QKT_ROWS 1088

typedef __attribute__((ext_vector_type(8))) short bf16x8;
typedef __attribute__((ext_vector_type(4))) float f32x4;

__device__ __forceinline__ void g2l16(const void* g, void* l) {
    __builtin_amdgcn_global_load_lds(
        (const __attribute__((address_space(1))) void*)g,
        (__attribute__((address_space(3))) void*)l, 16, 0, 0);
}

__device__ __forceinline__ ushort f2bfu(float x) {
    __hip_bfloat16 t = __float2bfloat16(x);
    return *reinterpret_cast<ushort*>(&t);
}

// ---------------------------------------------------------------------------
// Fused preps: [0,4096) x->Xb; [4096,4224) Wv cast; [4224,4352) Wqk cast;
// [4352,4872) Gcat; [4872,4888) Fcs; [4888,4898) Bas DFT basis table.
// ---------------------------------------------------------------------------
__global__ __launch_bounds__(256) void k_misc(const float* __restrict__ x,
                                              const float* __restrict__ wqkv,
                                              const float* __restrict__ wout,
                                              __hip_bfloat16* __restrict__ Xb,
                                              ushort* __restrict__ Wvb,
                                              ushort* __restrict__ Wqkb,
                                              ushort* __restrict__ Gcat,
                                              ushort* __restrict__ Fcs,
                                              ushort* __restrict__ Bas) {
    __shared__ float tc[128], ts[128];
    int tid = threadIdx.x;
    int bid = blockIdx.x;
    if (bid < 4096) {
        int i = bid * 256 + tid;
        float4 v = ((const float4*)x)[i];
        __hip_bfloat16 o[4] = {__float2bfloat16(v.x), __float2bfloat16(v.y),
                               __float2bfloat16(v.z), __float2bfloat16(v.w)};
        *(ushort4*)((ushort*)Xb + (size_t)i * 4) = *(const ushort4*)o;
    } else if (bid < 4224) {
        int u = bid - 4096;                // 0..127
        float4 v = *(const float4*)(wqkv + (size_t)u * 3072 + 2048 + tid * 4);
        ushort o[4] = {f2bfu(v.x), f2bfu(v.y), f2bfu(v.z), f2bfu(v.w)};
        *(ushort4*)(Wvb + (size_t)u * 1024 + tid * 4) = *(const ushort4*)o;
    } else if (bid < 4352) {
        int u = bid - 4224;                // 0..127: q/k cols 0..2047 of row u
        #pragma unroll
        for (int it = 0; it < 2; ++it) {
            int i = it * 256 + tid;        // float4 idx 0..511
            float4 v = ((const float4*)(wqkv + (size_t)u * 3072))[i];
            ushort o[4] = {f2bfu(v.x), f2bfu(v.y), f2bfu(v.z), f2bfu(v.w)};
            *(ushort4*)(Wqkb + (size_t)u * 2048 + i * 4) = *(const ushort4*)o;
        }
    } else if (bid < 4872) {
        int hx = bid - 4352;               // 0..519
        if (tid < 128) {
            float a = (float)tid / 64.0f;
            tc[tid] = cospif(a);
            ts[tid] = sinpif(a);
        }
        __syncthreads();
        if (tid < 128) {
            int h = hx / 65, xx = hx - h * 65;
            float w = (xx == 0 || xx == 64) ? (1.0f / 128.0f) : (2.0f / 128.0f);
            float ar = 0.f, ai = 0.f;
            #pragma unroll 8
            for (int d = 0; d < 128; ++d) {
                float wv = wout[(size_t)(h * 128 + d) * 128 + tid];
                int m = (xx * d) & 127;
                ar = fmaf(wv, tc[m], ar);
                ai = fmaf(wv, ts[m], ai);
            }
            ushort* gp = Gcat + ((size_t)(h * 128 + tid)) * 160;
            gp[xx] = f2bfu(ar * w);
            gp[80 + xx] = f2bfu(-ai * w);
            if (xx == 0) {
                for (int k = 65; k < 80; ++k) gp[k] = 0;
                for (int k = 145; k < 160; ++k) gp[k] = 0;
            }
        }
    } else if (bid < 4888) {
        // Fcs[r][y]: r<128 cos(2pi r y/128); r>=128 -sin(...); y>=65 -> 0
        int r = (bid - 4872) * 16 + (tid >> 4);
        int d = r & 127;
        int y0 = (tid & 15) * 6;
        #pragma unroll
        for (int k = 0; k < 6; ++k) {
            int y = y0 + k;
            float v = 0.f;
            if (y < 65) {
                float a = (float)((d * y) & 127) / 64.0f;
                v = (r < 128) ? cospif(a) : -sinpif(a);
            }
            Fcs[r * 96 + y] = f2bfu(v);
        }
    } else {
        // Bas[rj][d]: rj<80 -> cos(2pi f d/128)/65, rj>=80 -> -sin(...)/65, f=rj%80
        int idx = bid - 4888;              // 0..9
        int rj = idx * 16 + (tid >> 4);
        int ri = (rj >= 80) ? 1 : 0;
        int f = rj - ri * 80;
        int d0 = (tid & 15) * 8;
        #pragma unroll
        for (int k = 0; k < 8; ++k) {
            int d = d0 + k;
            float a = (float)((f * d) & 127) / 64.0f;
            float v = (ri ? -sinpif(a) : cospif(a)) * (1.0f / 65.0f);
            Bas[rj * 128 + d] = f2bfu(v);
        }
    }
}

// ---------------------------------------------------------------------------
// Weight DFT fold via MFMA. One block per (reg,h): C[c][rj] =
// sum_d Wqkb[c][reg*1024+h*128+d] * Bas[rj][d]. M=128 c, N=160 rj, K=128.
// Epilogue scatters to Wt packed layout, ushort4 over 4 consecutive c.
// ---------------------------------------------------------------------------
__global__ __launch_bounds__(256) void k_wfold(const ushort* __restrict__ Wqkb,
                                               const ushort* __restrict__ Bas,
                                               ushort* __restrict__ Wt) {
    __shared__ ushort As[128 * 128];
    __shared__ ushort Bs[160 * 128];
    int tid = threadIdx.x;
    int wave = tid >> 6, lane = tid & 63;
    int reg = blockIdx.x >> 3, h = blockIdx.x & 7;
    const ushort* ga = Wqkb + reg * 1024 + h * 128;   // row stride 2048
    #pragma unroll
    for (int it = 0; it < 8; ++it) {
        int q0 = wave * 512 + it * 64;
        int q = q0 + lane;
        int row = q >> 4, cp = q & 15;
        int gc = cp ^ (row & 15);
        g2l16(ga + (size_t)row * 2048 + gc * 8, As + q0 * 8);
    }
    #pragma unroll
    for (int it = 0; it < 10; ++it) {
        int q0 = it * 256 + wave * 64;
        int q = q0 + lane;
        int row = q >> 4, cp = q & 15;
        int gc = cp ^ (row & 15);
        g2l16(Bas + (size_t)row * 128 + gc * 8, Bs + q0 * 8);
    }
    __syncthreads();

    f32x4 acc[4][5];
    #pragma unroll
    for (int i = 0; i < 4; ++i)
        #pragma unroll
        for (int j = 0; j < 5; ++j) acc[i][j] = (f32x4){0.f, 0.f, 0.f, 0.f};

    int lr = lane & 15, lk = lane >> 4;
    int wr = (wave >> 1) * 64;             // m (c) offset
    int wn = (wave & 1) * 80;              // n (rj) offset
    #pragma unroll
    for (int kk = 0; kk < 4; ++kk) {
        bf16x8 af[4], bfr[5];
        int c = kk * 4 + lk;
        #pragma unroll
        for (int i = 0; i < 4; ++i) {
            int m = wr + i * 16 + lr;
            af[i] = *(const bf16x8*)(As + m * 128 + (c ^ (m & 15)) * 8);
        }
        #pragma unroll
        for (int j = 0; j < 5; ++j) {
            int n = wn + j * 16 + lr;
            bfr[j] = *(const bf16x8*)(Bs + n * 128 + (c ^ (n & 15)) * 8);
        }
        #pragma unroll
        for (int i = 0; i < 4; ++i)
            #pragma unroll
            for (int j = 0; j < 5; ++j)
                acc[i][j] = __builtin_amdgcn_mfma_f32_16x16x32_bf16(af[i], bfr[j], acc[i][j], 0, 0, 0);
    }

    #pragma unroll
    for (int j = 0; j < 5; ++j) {
        int rj = wn + j * 16 + lr;
        int ri = (rj >= 80) ? 1 : 0;
        int f = rj - ri * 80;
        if (f <= 64) {
            int F = h * 65 + f;
            int n = reg * 1056 + ((F >> 4) << 5) + (F & 15) + ri * 16;
            #pragma unroll
            for (int i = 0; i < 4; ++i) {
                int c0 = wr + i * 16 + lk * 4;
                union { ushort4 u4; ushort u[4]; } pk;
                #pragma unroll
                for (int r = 0; r < 4; ++r) pk.u[r] = f2bfu(acc[i][j][r]);
                *(ushort4*)(Wt + (size_t)n * 128 + c0) = pk.u4;
            }
        }
    }
}

// ---------------------------------------------------------------------------
// GEMM1 (MFMA): Xb[32768,128] @ Wt^T (q/k only). 128x128 tile, K=128 one shot.
// Epilogue: (re,im) same lane, adjacent j-tiles -> magnitude -> XQKT packed.
// ---------------------------------------------------------------------------
__global__ __launch_bounds__(256) void k_gemm1m(const __hip_bfloat16* __restrict__ Xb,
                                                const __hip_bfloat16* __restrict__ Wt,
                                                ushort* __restrict__ XQKT) {
    __shared__ ushort As[128 * 128];
    __shared__ ushort Bs[128 * 128];
    int tid = threadIdx.x;
    int wave = tid >> 6, lane = tid & 63;
    int n0 = blockIdx.x * 128;
    int m0 = blockIdx.y * 128;
    const ushort* ga = (const ushort*)Xb + (size_t)m0 * 128;
    const ushort* gb = (const ushort*)Wt + (size_t)n0 * 128;
    #pragma unroll
    for (int it = 0; it < 8; ++it) {
        int q = wave * 512 + it * 64 + lane;
        int row = q >> 4, cp = q & 15;
        int gc = cp ^ (row & 15);
        int lbase = (wave * 512 + it * 64) * 8;
        g2l16(ga + (size_t)row * 128 + gc * 8, As + lbase);
        g2l16(gb + (size_t)row * 128 + gc * 8, Bs + lbase);
    }
    __syncthreads();

    f32x4 acc[4][4];
    #pragma unroll
    for (int i = 0; i < 4; ++i)
        #pragma unroll
        for (int j = 0; j < 4; ++j) acc[i][j] = (f32x4){0.f, 0.f, 0.f, 0.f};

    int lr = lane & 15, lk = lane >> 4;
    int wr = (wave >> 1) * 64, wc = (wave & 1) * 64;
    #pragma unroll
    for (int kk = 0; kk < 4; ++kk) {
        bf16x8 af[4], bfr[4];
        int c = kk * 4 + lk;
        #pragma unroll
        for (int i = 0; i < 4; ++i) {
            int m = wr + i * 16 + lr;
            af[i] = *(const bf16x8*)(As + m * 128 + (c ^ (m & 15)) * 8);
            int n = wc + i * 16 + lr;
            bfr[i] = *(const bf16x8*)(Bs + n * 128 + (c ^ (n & 15)) * 8);
        }
        #pragma unroll
        for (int i = 0; i < 4; ++i)
            #pragma unroll
            for (int j = 0; j < 4; ++j)
                acc[i][j] = __builtin_amdgcn_mfma_f32_16x16x32_bf16(af[i], bfr[j], acc[i][j], 0, 0, 0);
    }

    #pragma unroll
    for (int i = 0; i < 4; ++i) {
        int gr = m0 + wr + i * 16 + lk * 4;
        #pragma unroll
        for (int jp = 0; jp < 2; ++jp) {
            int cb = n0 + wc + jp * 32;
            if (cb < 2112) {
                int region = (cb >= 1056) ? 1 : 0;
                int local = cb - region * 1056;
                int row = region * 528 + ((local >> 5) << 4) + lr;
                f32x4 re = acc[i][2 * jp], im = acc[i][2 * jp + 1];
                union { ushort4 u4; ushort u[4]; } pk;
                #pragma unroll
                for (int r = 0; r < 4; ++r)
                    pk.u[r] = f2bfu(sqrtf(re[r] * re[r] + im[r] * im[r]));
                *(ushort4*)(XQKT + (size_t)row * MROWS + gr) = pk.u4;
            }
        }
    }
}

// ---------------------------------------------------------------------------
// QK^T partials via MFMA. Grid (bh=128, ch=8 e-chunks of 256), 5 waves/block.
// Stage once per block, coalesced (2 rows x 32 lanes of 512 B per instr),
// XOR chunk swizzle on global side. Wave w computes tile-row w over 256 e.
// ---------------------------------------------------------------------------
__global__ __launch_bounds__(320) void k_attq(const ushort* __restrict__ XQKT,
                                              float* __restrict__ attp) {
    __shared__ ushort S[144 * 256];        // 73728 B
    int tid = threadIdx.x;
    int wave = tid >> 6, lane = tid & 63;
    int bh = blockIdx.x, ch = blockIdx.y;
    int b = bh >> 3, h = bh & 7;
    int qrow0 = h * 65, krow0 = 528 + h * 65;
    int lr = lane & 15, quad = lane >> 4;
    size_t ebase = (size_t)b * NSEQ + ch * 256;
    int lrow = lane >> 5;
    int lch = lane & 31;

    for (int i = wave; i < 66; i += 5) {
        int qk = (i >= 33) ? 1 : 0;
        int pi = i - 33 * qk;
        int lrow0 = qk * 72 + pi * 2;
        int row = lrow0 + lrow;
        int grow = (qk ? krow0 : qrow0) + pi * 2 + lrow;
        int gc = lch ^ (row & 7);
        g2l16(XQKT + (size_t)grow * MROWS + ebase + gc * 8, S + lrow0 * 256);
    }
    __syncthreads();

    f32x4 acc[5];
    #pragma unroll
    for (int j = 0; j < 5; ++j) acc[j] = (f32x4){0.f, 0.f, 0.f, 0.f};
    int tr = wave;
    int arow = tr * 16 + lr;
    #pragma unroll
    for (int ks = 0; ks < 8; ++ks) {
        int pc = (ks * 4 + quad) ^ (lr & 7);
        bf16x8 af = *(const bf16x8*)(S + arow * 256 + pc * 8);
        bf16x8 bfr[5];
        #pragma unroll
        for (int tc = 0; tc < 5; ++tc)
            bfr[tc] = *(const bf16x8*)(S + (72 + tc * 16 + lr) * 256 + pc * 8);
        #pragma unroll
        for (int tc = 0; tc < 5; ++tc)
            acc[tc] = __builtin_amdgcn_mfma_f32_16x16x32_bf16(af, bfr[tc], acc[tc], 0, 0, 0);
    }

    float* outp = attp + ((size_t)bh * 8 + ch) * 6400;
    #pragma unroll
    for (int tc = 0; tc < 5; ++tc)
        #pragma unroll
        for (int r = 0; r < 4; ++r)
            outp[(tr * 16 + quad * 4 + r) * 80 + tc * 16 + lr] = acc[tc][r];
}

// ---------------------------------------------------------------------------
// Sum 8 partials + softmax over y -> AttB bf16 [80x104] zero-padded.
// ---------------------------------------------------------------------------
__global__ void k_softmax(const float* __restrict__ attp, ushort* __restrict__ AttB) {
    int xx = blockIdx.x;                   // 0..79
    int bh = blockIdx.y;                   // 0..127
    int lane = threadIdx.x;                // 64
    ushort* Ab = AttB + (size_t)bh * 8320;
    if (xx >= 65) {
        Ab[xx * 104 + lane] = 0;
        if (lane < 40) Ab[xx * 104 + 64 + lane] = 0;
        return;
    }
    const float* base = attp + (size_t)bh * 8 * 6400 + xx * 80;
    float v0 = 0.f, v1 = 0.f;
    #pragma unroll
    for (int c = 0; c < 8; ++c) {
        v0 += base[(size_t)c * 6400 + lane];
        if (lane == 0) v1 += base[(size_t)c * 6400 + 64];
    }
    float v1b = __shfl(v1, 0);
    float m = fmaxf(v0, v1b);
    #pragma unroll
    for (int off = 32; off >= 1; off >>= 1) m = fmaxf(m, __shfl_xor(m, off));
    float e0 = expf(v0 - m);
    float e1 = expf(v1b - m);
    float s = e0;
    #pragma unroll
    for (int off = 32; off >= 1; off >>= 1) s += __shfl_xor(s, off);
    s += e1;
    float inv = 1.0f / s;
    Ab[xx * 104 + lane] = f2bfu(e0 * inv);
    if (lane == 0) Ab[xx * 104 + 64] = f2bfu(e1 * inv);
    if (lane < 39) Ab[xx * 104 + 65 + lane] = 0;
}

// ---------------------------------------------------------------------------
// Fused T+P per (chalf, bh) block (reads bf16 AttB straight from global):
// Stage 1: [Fc;Fs][256,96] @ AttB^T -> A3 via LDS (C->A layout, pads zeroed)
// Stage 2: A3[128,160] @ Gcat^T -> Pt[b][c][h*128+d]
// ---------------------------------------------------------------------------
__global__ __launch_bounds__(256) void k_TP(const ushort* __restrict__ AttB,
                                            const ushort* __restrict__ Fcs,
                                            const ushort* __restrict__ Gcat,
                                            ushort* __restrict__ Pt) {
    __shared__ ushort A3[128 * 168];
    int tid = threadIdx.x;
    int wave = tid >> 6, lane = tid & 63;
    int lr = lane & 15, quad = lane >> 4;
    int chalf = blockIdx.x, bh = blockIdx.y;
    int b = bh >> 3, h = bh & 7;

    uint2 z2; z2.x = 0; z2.y = 0;
    uint2* A3v = (uint2*)A3;
    #pragma unroll 4
    for (int i = tid; i < 128 * 168 / 4; i += 256) A3v[i] = z2;
    __syncthreads();
    const ushort* Ab = AttB + (size_t)bh * 8320;

    // stage 1
    f32x4 acc1[4][5];
    #pragma unroll
    for (int i = 0; i < 4; ++i)
        #pragma unroll
        for (int j = 0; j < 5; ++j) acc1[i][j] = (f32x4){0.f, 0.f, 0.f, 0.f};
    #pragma unroll
    for (int ks = 0; ks < 3; ++ks) {
        bf16x8 af[4], bfr[5];
        #pragma unroll
        for (int mi = 0; mi < 4; ++mi)
            af[mi] = *(const bf16x8*)(Fcs + (size_t)((wave * 4 + mi) * 16 + lr) * 96 + ks * 32 + quad * 8);
        #pragma unroll
        for (int nt = 0; nt < 5; ++nt)
            bfr[nt] = *(const bf16x8*)(Ab + (nt * 16 + lr) * 104 + ks * 32 + quad * 8);
        #pragma unroll
        for (int mi = 0; mi < 4; ++mi)
            #pragma unroll
            for (int nt = 0; nt < 5; ++nt)
                acc1[mi][nt] = __builtin_amdgcn_mfma_f32_16x16x32_bf16(af[mi], bfr[nt], acc1[mi][nt], 0, 0, 0);
    }
    #pragma unroll
    for (int nt = 0; nt < 5; ++nt) {
        int x = nt * 16 + lr;
        if (x < 65) {
            #pragma unroll
            for (int mi = 0; mi < 4; ++mi) {
                int wbase = (wave * 4 + mi) * 16 + quad * 4;
                #pragma unroll
                for (int r = 0; r < 4; ++r) {
                    int which = wbase + r;
                    int d = which & 127;
                    int kc = (which >> 7) * 80 + x;
                    A3[d * 168 + kc] = f2bfu(acc1[mi][nt][r]);
                }
            }
        }
    }
    __syncthreads();

    // stage 2
    f32x4 acc2[2][4];
    #pragma unroll
    for (int i = 0; i < 2; ++i)
        #pragma unroll
        for (int j = 0; j < 4; ++j) acc2[i][j] = (f32x4){0.f, 0.f, 0.f, 0.f};
    const ushort* Gh = Gcat + (size_t)h * 128 * 160;
    #pragma unroll
    for (int ks = 0; ks < 5; ++ks) {
        bf16x8 a2[2], b2[4];
        #pragma unroll
        for (int mi = 0; mi < 2; ++mi)
            a2[mi] = *(const bf16x8*)(A3 + ((wave * 2 + mi) * 16 + lr) * 168 + ks * 32 + quad * 8);
        #pragma unroll
        for (int nt = 0; nt < 4; ++nt)
            b2[nt] = *(const bf16x8*)(Gh + (size_t)(chalf * 64 + nt * 16 + lr) * 160 + ks * 32 + quad * 8);
        #pragma unroll
        for (int mi = 0; mi < 2; ++mi)
            #pragma unroll
            for (int nt = 0; nt < 4; ++nt)
                acc2[mi][nt] = __builtin_amdgcn_mfma_f32_16x16x32_bf16(a2[mi], b2[nt], acc2[mi][nt], 0, 0, 0);
    }
    #pragma unroll
    for (int mi = 0; mi < 2; ++mi) {
        int dbase = (wave * 2 + mi) * 16 + quad * 4;
        #pragma unroll
        for (int nt = 0; nt < 4; ++nt) {
            int c = chalf * 64 + nt * 16 + lr;
            union { ushort4 u4; ushort u[4]; } pk;
            #pragma unroll
            for (int r = 0; r < 4; ++r) pk.u[r] = f2bfu(acc2[mi][nt][r]);
            *(ushort4*)(Pt + ((size_t)(b * 128 + c)) * 1024 + h * 128 + dbase) = pk.u4;
        }
    }
}

// ---------------------------------------------------------------------------
// R_b = Wv @ P_b folded: Rt_b[n][u] = sum_vc Wvb[u][vc] * Pt_b[n][vc].
// ---------------------------------------------------------------------------
__global__ __launch_bounds__(256) void k_R(const ushort* __restrict__ Wvb,
                                           const ushort* __restrict__ Pt,
                                           ushort* __restrict__ Rt) {
    __shared__ ushort As[128 * 128];
    __shared__ ushort Bs[128 * 128];
    int tid = threadIdx.x;
    int wave = tid >> 6, lane = tid & 63;
    int b = blockIdx.x;
    const ushort* pb = Pt + (size_t)b * 128 * 1024;

    f32x4 acc[4][4];
    #pragma unroll
    for (int i = 0; i < 4; ++i)
        #pragma unroll
        for (int j = 0; j < 4; ++j) acc[i][j] = (f32x4){0.f, 0.f, 0.f, 0.f};

    int lr = lane & 15, lk = lane >> 4;
    int wr = (wave >> 1) * 64, wc = (wave & 1) * 64;

    for (int k0 = 0; k0 < 1024; k0 += 128) {
        __syncthreads();
        #pragma unroll
        for (int it = 0; it < 8; ++it) {
            int q = wave * 512 + it * 64 + lane;
            int row = q >> 4, cp = q & 15;
            int gc = cp ^ (row & 15);
            int lbase = (wave * 512 + it * 64) * 8;
            g2l16(Wvb + (size_t)row * 1024 + k0 + gc * 8, As + lbase);
            g2l16(pb + (size_t)row * 1024 + k0 + gc * 8, Bs + lbase);
        }
        __syncthreads();
        #pragma unroll
        for (int kk = 0; kk < 4; ++kk) {
            bf16x8 af[4], bfr[4];
            int c = kk * 4 + lk;
            #pragma unroll
            for (int i = 0; i < 4; ++i) {
                int m = wr + i * 16 + lr;
                af[i] = *(const bf16x8*)(As + m * 128 + (c ^ (m & 15)) * 8);
                int n = wc + i * 16 + lr;
                bfr[i] = *(const bf16x8*)(Bs + n * 128 + (c ^ (n & 15)) * 8);
            }
            #pragma unroll
            for (int i = 0; i < 4; ++i)
                #pragma unroll
                for (int j = 0; j < 4; ++j)
                    acc[i][j] = __builtin_amdgcn_mfma_f32_16x16x32_bf16(af[i], bfr[j], acc[i][j], 0, 0, 0);
        }
    }
    #pragma unroll
    for (int i = 0; i < 4; ++i) {
        int ubase = wr + i * 16 + lk * 4;
        #pragma unroll
        for (int j = 0; j < 4; ++j) {
            int n = wc + j * 16 + lr;
            union { ushort4 u4; ushort u[4]; } pk;
            #pragma unroll
            for (int r = 0; r < 4; ++r) pk.u[r] = f2bfu(acc[i][j][r]);
            *(ushort4*)(Rt + (size_t)b * 16384 + n * 128 + ubase) = pk.u4;
        }
    }
}

// ---------------------------------------------------------------------------
// out = Xb @ Rt_b^T + bias. M=32768 (128/block), N=128, K=128 one shot.
// ---------------------------------------------------------------------------
__global__ __launch_bounds__(256) void k_out(const __hip_bfloat16* __restrict__ Xb,
                                             const ushort* __restrict__ Rt,
                                             const float* __restrict__ bout,
                                             float* __restrict__ out) {
    __shared__ ushort As[128 * 128];
    __shared__ ushort Bs[128 * 128];
    int tid = threadIdx.x;
    int wave = tid >> 6, lane = tid & 63;
    int m0 = blockIdx.x * 128;
    int b = blockIdx.x >> 4;
    const ushort* ga = (const ushort*)Xb + (size_t)m0 * 128;
    const ushort* gb = Rt + (size_t)b * 16384;
    #pragma unroll
    for (int it = 0; it < 8; ++it) {
        int q = wave * 512 + it * 64 + lane;
        int row = q >> 4, cp = q & 15;
        int gc = cp ^ (row & 15);
        int lbase = (wave * 512 + it * 64) * 8;
        g2l16(ga + (size_t)row * 128 + gc * 8, As + lbase);
        g2l16(gb + (size_t)row * 128 + gc * 8, Bs + lbase);
    }
    __syncthreads();

    f32x4 acc[4][4];
    #pragma unroll
    for (int i = 0; i < 4; ++i)
        #pragma unroll
        for (int j = 0; j < 4; ++j) acc[i][j] = (f32x4){0.f, 0.f, 0.f, 0.f};

    int lr = lane & 15, lk = lane >> 4;
    int wr = (wave >> 1) * 64, wc = (wave & 1) * 64;
    #pragma unroll
    for (int kk = 0; kk < 4; ++kk) {
        bf16x8 af[4], bfr[4];
        int c = kk * 4 + lk;
        #pragma unroll
        for (int i = 0; i < 4; ++i) {
            int m = wr + i * 16 + lr;
            af[i] = *(const bf16x8*)(As + m * 128 + (c ^ (m & 15)) * 8);
            int n = wc + i * 16 + lr;
            bfr[i] = *(const bf16x8*)(Bs + n * 128 + (c ^ (n & 15)) * 8);
        }
        #pragma unroll
        for (int i = 0; i < 4; ++i)
            #pragma unroll
            for (int j = 0; j < 4; ++j)
                acc[i][j] = __builtin_amdgcn_mfma_f32_16x16x32_bf16(af[i], bfr[j], acc[i][j], 0, 0, 0);
    }

    #pragma unroll
    for (int i = 0; i < 4; ++i) {
        int gr = m0 + wr + i * 16 + lk * 4;
        #pragma unroll
        for (int j = 0; j < 4; ++j) {
            int gcol = wc + j * 16 + lr;
            float bias = bout[gcol];
            #pragma unroll
            for (int r = 0; r < 4; ++r)
                out[(size_t)(gr + r) * 128 + gcol] = acc[i][j][r] + bias;
        }
    }
}

extern "C" void kernel_launch(void* const* d_in, const int* in_sizes, int n_in,
                              void* d_out, int out_size, void* d_ws, size_t ws_size,
                              hipStream_t stream) {
    const float* x    = (const float*)d_in[0];
    const float* wqkv = (const float*)d_in[1];
    const float* wout = (const float*)d_in[2];
    const float* bout = (const float*)d_in[3];
    float* out = (float*)d_out;

    char* ws = (char*)d_ws;
    size_t off = 0;
    auto alloc = [&](size_t bytes) -> void* {
        void* p = (void*)(ws + off);
        off += (bytes + 255) & ~(size_t)255;
        return p;
    };
    __hip_bfloat16* Wt = (__hip_bfloat16*)alloc((size_t)NPAD * 128 * 2);       // 0.56 MB
    ushort* Gcat = (ushort*)alloc((size_t)8 * 128 * 160 * 2);                  // 320 KB
    ushort* Fcs  = (ushort*)alloc((size_t)256 * 96 * 2);                       // 48 KB
    ushort* Wvb  = (ushort*)alloc((size_t)128 * 1024 * 2);                     // 256 KB
    ushort* Wqkb = (ushort*)alloc((size_t)128 * 2048 * 2);                     // 512 KB
    ushort* Bas  = (ushort*)alloc((size_t)160 * 128 * 2);                      // 40 KB
    ushort* XQKT = (ushort*)alloc((size_t)QKT_ROWS * MROWS * 2);               // 71.3 MB
    __hip_bfloat16* Xb = (__hip_bfloat16*)alloc((size_t)MROWS * 128 * 2);      // 8.4 MB
    float* attp = (float*)alloc((size_t)128 * 8 * 6400 * 4);                   // 26.2 MB
    ushort* AttB = (ushort*)alloc((size_t)128 * 8320 * 2);                     // 2.13 MB
    ushort* Pt  = (ushort*)alloc((size_t)16 * 128 * 1024 * 2);                 // 4.2 MB
    ushort* Rt  = (ushort*)alloc((size_t)16 * 128 * 128 * 2);                  // 512 KB

    k_misc<<<dim3(4898), 256, 0, stream>>>(x, wqkv, wout, Xb, Wvb, Wqkb, Gcat, Fcs, Bas);
    k_wfold<<<dim3(16), 256, 0, stream>>>(Wqkb, Bas, (ushort*)Wt);
    k_gemm1m<<<dim3(17, 256), 256, 0, stream>>>(Xb, Wt, XQKT);
    k_attq<<<dim3(128, 8), 320, 0, stream>>>(XQKT, attp);
    k_softmax<<<dim3(80, 128), 64, 0, stream>>>(attp, AttB);
    k_TP<<<dim3(2, 128), 256, 0, stream>>>(AttB, Fcs, Gcat, Pt);
    k_R<<<dim3(16), 256, 0, stream>>>(Wvb, Pt, Rt);
    k_out<<<dim3(256), 256, 0, stream>>>(Xb, Rt, bout, out);
}